// Round 10
// baseline (1651.619 us; speedup 1.0000x reference)
//
#include <hip/hip_runtime.h>
#include <math.h>

// Problem constants
#define kB 64
#define kC 1024
#define kT 128
#define kLayers 8
#define kPos 33
#define kEv 16
#define kPar 57

#define BM 128
#define kOB (kC / BM)   // o-blocks per layer = 8
#define NTHR 256

#define SLAB ((size_t)kB * kC * kT)   // 8,388,608 elements

typedef __attribute__((ext_vector_type(8))) short short8v;
typedef __attribute__((ext_vector_type(4))) float float4v;
typedef __attribute__((ext_vector_type(4))) unsigned short ushort4v;

// RNE fp32 -> bf16 (bits) and back; hi/lo split: f = hi + lo + O(2^-18 |f|)
__device__ __forceinline__ unsigned short bf_hi(float f) {
    unsigned int x = __float_as_uint(f);
    unsigned int r = x + 0x7fffu + ((x >> 16) & 1u);
    return (unsigned short)(r >> 16);
}
__device__ __forceinline__ float bf_f(unsigned short u) {
    return __uint_as_float(((unsigned int)u) << 16);
}

// ---------------------------------------------------------------------------
// Positional-encoding projection (verified r3/r4)
// ---------------------------------------------------------------------------
__global__ void pos_kernel(const float* __restrict__ w_pos,
                           const float* __restrict__ b_pos,
                           float* __restrict__ posproj) {
    int o = blockIdx.x;
    int t = threadIdx.x;
    float ramp = -1.0f + 2.0f * (float)t / (float)(kT - 1);
    const float* wr = w_pos + (size_t)o * kPos;
    float s = b_pos[o] + wr[0] * ramp;
    float p2 = 1.0f;
#pragma unroll
    for (int i = 0; i < 16; ++i) {
        float sv, cv;
        sincosf(p2 * ramp, &sv, &cv);
        s += wr[1 + 2 * i] * sv + wr[2 + 2 * i] * cv;
        p2 *= 2.0f;
    }
    posproj[(size_t)o * kT + t] = s;
}

// ---------------------------------------------------------------------------
// Mt = (w_par @ w_vec) transposed, pbias = w_par @ b_vec (verified r3/r4)
// ---------------------------------------------------------------------------
__global__ void mt_kernel(const float* __restrict__ w_par,
                          const float* __restrict__ w_vec,
                          const float* __restrict__ b_vec,
                          float* __restrict__ Mt,
                          float* __restrict__ pbias) {
    if (blockIdx.x == kPar) {
        int p = threadIdx.x;
        if (p < kPar) {
            float s = 0.f;
            for (int c = 0; c < kC; ++c) s += w_par[(size_t)p * kC + c] * b_vec[c];
            pbias[p] = s;
        }
        return;
    }
    int p = blockIdx.x;
    int k = threadIdx.x * 4;
    float mx = 0.f, my = 0.f, mz = 0.f, mw = 0.f;
    for (int o = 0; o < kC; ++o) {
        float wp = w_par[(size_t)p * kC + o];
        float4 wv = *(const float4*)(w_vec + (size_t)o * kC + k);
        mx += wp * wv.x; my += wp * wv.y; mz += wp * wv.z; mw += wp * wv.w;
    }
    Mt[(size_t)(k + 0) * kPar + p] = mx;
    Mt[(size_t)(k + 1) * kPar + p] = my;
    Mt[(size_t)(k + 2) * kPar + p] = mz;
    Mt[(size_t)(k + 3) * kPar + p] = mw;
}

// ---------------------------------------------------------------------------
// Weight pre-convert: enc_w layer [o][c][tap] fp32 -> wpl[hi_t0,hi_t1,lo_t0,lo_t1][o][c]
// ---------------------------------------------------------------------------
__global__ void wconv_kernel(const float* __restrict__ src,
                             unsigned short* __restrict__ wpl) {
    int o = blockIdx.x;
    int tid = threadIdx.x;
    const float* r = src + (size_t)o * (2 * kC) + tid * 8;
    float4 v0 = *(const float4*)r;
    float4 v1 = *(const float4*)(r + 4);
    float t0v[4] = {v0.x, v0.z, v1.x, v1.z};   // tap0
    float t1v[4] = {v0.y, v0.w, v1.y, v1.w};   // tap1
    int c0 = tid * 4;
    ushort4v h0, l0, h1, l1;
#pragma unroll
    for (int j = 0; j < 4; ++j) {
        unsigned short h = bf_hi(t0v[j]); h0[j] = h; l0[j] = bf_hi(t0v[j] - bf_f(h));
        unsigned short g = bf_hi(t1v[j]); h1[j] = g; l1[j] = bf_hi(t1v[j] - bf_f(g));
    }
    size_t base = (size_t)o * kC + c0;
    const size_t P = (size_t)kC * kC;
    *(ushort4v*)&wpl[base] = h0;
    *(ushort4v*)&wpl[base + P] = h1;
    *(ushort4v*)&wpl[base + 2 * P] = l0;
    *(ushort4v*)&wpl[base + 3 * P] = l1;
}

// ---------------------------------------------------------------------------
// w_spec [o][c] fp32 -> wsp [hi,lo][o][c] bf16
// ---------------------------------------------------------------------------
__global__ void wspec_kernel(const float* __restrict__ src,
                             unsigned short* __restrict__ wsp) {
    int o = blockIdx.x;
    int c0 = threadIdx.x * 4;
    float4 v = *(const float4*)(src + (size_t)o * kC + c0);
    float f[4] = {v.x, v.y, v.z, v.w};
    ushort4v hh, ll;
#pragma unroll
    for (int j = 0; j < 4; ++j) {
        unsigned short h = bf_hi(f[j]); hh[j] = h; ll[j] = bf_hi(f[j] - bf_f(h));
    }
    size_t base = (size_t)o * kC + c0;
    *(ushort4v*)&wsp[base] = hh;
    *(ushort4v*)&wsp[base + (size_t)kC * kC] = ll;
}

// ---------------------------------------------------------------------------
// Transpose fp32 [b][c][t] -> bf16 hi/lo planes [pl][b][t][c] (for x only)
// ---------------------------------------------------------------------------
__global__ void trans0_kernel(const float* __restrict__ hsrc,
                              unsigned short* __restrict__ tpl) {
    __shared__ float tile[64][68];
    int b = blockIdx.x;
    int c0 = blockIdx.y * 64;
    int t0 = blockIdx.z * 64;
    int tid = threadIdx.x;
#pragma unroll
    for (int r = 0; r < 4; ++r) {
        int row = r * 16 + (tid >> 4);
        int col = (tid & 15) * 4;
        size_t idx = ((size_t)b * kC + c0 + row) * kT + t0 + col;
        float4 v = *(const float4*)&hsrc[idx];
        *(float4*)&tile[row][col] = v;
    }
    __syncthreads();
    unsigned short* thi = tpl;
    unsigned short* tlo = tpl + SLAB;
#pragma unroll
    for (int r = 0; r < 2; ++r) {
        int trow = r * 32 + (tid >> 3);
        int cc = (tid & 7) * 8;
        short8v hp, lp;
#pragma unroll
        for (int j = 0; j < 8; ++j) {
            float f = tile[cc + j][trow];
            unsigned short h = bf_hi(f);
            hp[j] = (short)h;
            lp[j] = (short)bf_hi(f - bf_f(h));
        }
        size_t dst = ((size_t)b * kT + t0 + trow) * kC + c0 + cc;
        *(short8v*)&thi[dst] = hp;
        *(short8v*)&tlo[dst] = lp;
    }
}

// ---------------------------------------------------------------------------
// Spec MFMA GEMM: S[o][t] = sum_c w_spec[o][c] x[c][t] (split-bf16, 3 products)
// Epilogue: + b_spec + posproj -> H0 planes (unnormalized h0, rn0 == 1).
// ---------------------------------------------------------------------------
__global__ __launch_bounds__(NTHR, 2) void spec_mfma(
    const unsigned short* __restrict__ xt,    // [2][b][t][c]
    const unsigned short* __restrict__ wsp,   // [2][o][c]
    const float* __restrict__ b_spec,
    const float* __restrict__ posproj,
    unsigned short* __restrict__ tplo) {
    __shared__ short Asl[128 * 64];   // 16 KB
    __shared__ short Bsl[128 * 64];   // 16 KB
    const int tid = threadIdx.x;
    const int obase = blockIdx.x * BM;
    const int b = blockIdx.y;
    const int lane = tid & 63;
    const int w = tid >> 6;
    const int r16 = lane & 15;
    const int kq = lane >> 4;
    const int mrow = (w & 1) * 64;
    const int ncol = (w >> 1) * 64;

    float4v acc[4][4];
#pragma unroll
    for (int m = 0; m < 4; ++m)
#pragma unroll
        for (int n = 0; n < 4; ++n) {
            float4v z = {0.f, 0.f, 0.f, 0.f};
            acc[m][n] = z;
        }

    for (int kc = 0; kc < kC; kc += 32) {
        __syncthreads();
#pragma unroll
        for (int r = 0; r < 4; ++r) {   // stage A: 128 o x 8 chunks
            int cw = r * 256 + tid;
            int g = cw & 7;
            int o = cw >> 3;
            size_t src = ((size_t)(g & 1) * kC + (obase + o)) * kC + kc + ((g >> 1) << 3);
            short8v v = *(const short8v*)&wsp[src];
            *(short8v*)&Asl[o * 64 + ((g ^ (o & 7)) << 3)] = v;
        }
#pragma unroll
        for (int r = 0; r < 4; ++r) {   // stage B: 128 t x 8 chunks
            int cw = r * 256 + tid;
            int g = cw & 7;
            int t = cw >> 3;
            size_t src = (size_t)(g & 1) * SLAB + ((size_t)b * kT + t) * kC + kc + ((g >> 1) << 3);
            short8v v = *(const short8v*)&xt[src];
            *(short8v*)&Bsl[t * 64 + ((g ^ (t & 7)) << 3)] = v;
        }
        __syncthreads();
        short8v ah[4], al[4], bh[4], bl[4];
#pragma unroll
        for (int m = 0; m < 4; ++m) {
            int ol = mrow + m * 16 + r16;
            const short* rowp = &Asl[ol * 64];
            ah[m] = *(const short8v*)&rowp[(((kq << 1)) ^ (ol & 7)) << 3];
            al[m] = *(const short8v*)&rowp[(((kq << 1) | 1) ^ (ol & 7)) << 3];
        }
#pragma unroll
        for (int n = 0; n < 4; ++n) {
            int tr = ncol + n * 16 + r16;
            const short* rowp = &Bsl[tr * 64];
            bh[n] = *(const short8v*)&rowp[(((kq << 1)) ^ (tr & 7)) << 3];
            bl[n] = *(const short8v*)&rowp[(((kq << 1) | 1) ^ (tr & 7)) << 3];
        }
#pragma unroll
        for (int m = 0; m < 4; ++m)
#pragma unroll
            for (int n = 0; n < 4; ++n) {
                acc[m][n] = __builtin_amdgcn_mfma_f32_16x16x32_bf16(ah[m], bh[n], acc[m][n], 0, 0, 0);
                acc[m][n] = __builtin_amdgcn_mfma_f32_16x16x32_bf16(ah[m], bl[n], acc[m][n], 0, 0, 0);
                acc[m][n] = __builtin_amdgcn_mfma_f32_16x16x32_bf16(al[m], bh[n], acc[m][n], 0, 0, 0);
            }
    }

    // epilogue: C/D layout col=lane&15 (t), row=(lane>>4)*4+reg (o)
    unsigned short* thi = tplo;
    unsigned short* tlo = tplo + SLAB;
#pragma unroll
    for (int m = 0; m < 4; ++m) {
        int ob4 = obase + mrow + m * 16 + kq * 4;
        float4v bias = *(const float4v*)&b_spec[ob4];
#pragma unroll
        for (int n = 0; n < 4; ++n) {
            int t = ncol + n * 16 + r16;
            ushort4v hh, hl;
#pragma unroll
            for (int j = 0; j < 4; ++j) {
                float v = acc[m][n][j] + bias[j] + posproj[(size_t)(ob4 + j) * kT + t];
                unsigned short h = bf_hi(v);
                hh[j] = h;
                hl[j] = bf_hi(v - bf_f(h));
            }
            size_t sidx = ((size_t)b * kT + t) * kC + ob4;
            *(ushort4v*)&thi[sidx] = hh;
            *(ushort4v*)&tlo[sidx] = hl;
        }
    }
}

// ---------------------------------------------------------------------------
// Conv layer, factored-norm: S0/S1 from UNNORMALIZED planes in separate accs;
// conv = rn[t]*S0 + rn[t+d]*S1; hp = leaky(conv+bias) + rn[t]*Hprev;
// writes Hout planes (split hp), ssp partials, and acc (+= rn*Hprev = h_prev).
// accmode: 0 none, 1 init, 2 add.
// ---------------------------------------------------------------------------
template <int DIL, int FIRST>
__global__ __launch_bounds__(NTHR, 2) void conv_mfma(
    const unsigned short* __restrict__ tpli,  // [2][b][t][c] unnormalized H_{i-1}
    const unsigned short* __restrict__ wpl,   // [hi_t0,hi_t1,lo_t0,lo_t1][o][c]
    const float* __restrict__ bconv,
    const float* __restrict__ rn,             // rn_{i-1} [b][t] (FIRST: unused)
    unsigned short* __restrict__ tplo,        // [2][b][t][c] unnormalized H_i
    float* __restrict__ ssp,                  // [kOB][b][t] sumsq partials of hp_i
    float* __restrict__ accp,                 // [b][c][t]
    int accmode) {
    __shared__ short Asl[2 * 128 * 64];   // 32 KB
    __shared__ short Bsl[192 * 64];       // 24 KB
    __shared__ float red[1024];           // 4 KB
    const int tid = threadIdx.x;
    const int obase = blockIdx.x * BM;
    const int b = blockIdx.y;
    const int lane = tid & 63;
    const int w = tid >> 6;
    const int r16 = lane & 15;
    const int kq = lane >> 4;
    const int mrow = (w & 1) * 64;
    const int ncol = (w >> 1) * 64;

    float4v acc0[4][4], acc1[4][4];
#pragma unroll
    for (int m = 0; m < 4; ++m)
#pragma unroll
        for (int n = 0; n < 4; ++n) {
            float4v z = {0.f, 0.f, 0.f, 0.f};
            acc0[m][n] = z;
            acc1[m][n] = z;
        }

    {   // zero B rows 128..191 once (t >= T -> 0)
        short8v z = {0, 0, 0, 0, 0, 0, 0, 0};
#pragma unroll
        for (int r = 0; r < 2; ++r) {
            int cw = r * 256 + tid;
            int t = 128 + (cw >> 3);
            int g = cw & 7;
            *(short8v*)&Bsl[t * 64 + ((g ^ (t & 7)) << 3)] = z;
        }
    }

    for (int kc = 0; kc < kC; kc += 32) {
        __syncthreads();
#pragma unroll
        for (int r = 0; r < 8; ++r) {   // stage A: 2 taps x 128 o x 8 chunks
            int cw = r * 256 + tid;
            int g = cw & 7;
            int o = (cw >> 3) & 127;
            int tap = cw >> 10;
            size_t src = ((size_t)((g & 1) * 2 + tap) * kC + (obase + o)) * kC + kc + ((g >> 1) << 3);
            short8v v = *(const short8v*)&wpl[src];
            *(short8v*)&Asl[tap * 8192 + o * 64 + ((g ^ (o & 7)) << 3)] = v;
        }
#pragma unroll
        for (int r = 0; r < 4; ++r) {   // stage B: 128 t x 8 chunks
            int cw = r * 256 + tid;
            int g = cw & 7;
            int t = cw >> 3;
            size_t src = (size_t)(g & 1) * SLAB + ((size_t)b * kT + t) * kC + kc + ((g >> 1) << 3);
            short8v v = *(const short8v*)&tpli[src];
            *(short8v*)&Bsl[t * 64 + ((g ^ (t & 7)) << 3)] = v;
        }
        __syncthreads();
        {   // tap 0 -> acc0
            short8v ah[4], al[4], bh[4], bl[4];
#pragma unroll
            for (int m = 0; m < 4; ++m) {
                int ol = mrow + m * 16 + r16;
                const short* rowp = &Asl[ol * 64];
                ah[m] = *(const short8v*)&rowp[(((kq << 1)) ^ (ol & 7)) << 3];
                al[m] = *(const short8v*)&rowp[(((kq << 1) | 1) ^ (ol & 7)) << 3];
            }
#pragma unroll
            for (int n = 0; n < 4; ++n) {
                int tr = ncol + n * 16 + r16;
                const short* rowp = &Bsl[tr * 64];
                bh[n] = *(const short8v*)&rowp[(((kq << 1)) ^ (tr & 7)) << 3];
                bl[n] = *(const short8v*)&rowp[(((kq << 1) | 1) ^ (tr & 7)) << 3];
            }
#pragma unroll
            for (int m = 0; m < 4; ++m)
#pragma unroll
                for (int n = 0; n < 4; ++n) {
                    acc0[m][n] = __builtin_amdgcn_mfma_f32_16x16x32_bf16(ah[m], bh[n], acc0[m][n], 0, 0, 0);
                    acc0[m][n] = __builtin_amdgcn_mfma_f32_16x16x32_bf16(ah[m], bl[n], acc0[m][n], 0, 0, 0);
                    acc0[m][n] = __builtin_amdgcn_mfma_f32_16x16x32_bf16(al[m], bh[n], acc0[m][n], 0, 0, 0);
                }
        }
        {   // tap 1 -> acc1 (shifted B rows)
            short8v ah[4], al[4], bh[4], bl[4];
#pragma unroll
            for (int m = 0; m < 4; ++m) {
                int ol = mrow + m * 16 + r16;
                const short* rowp = &Asl[8192 + ol * 64];
                ah[m] = *(const short8v*)&rowp[(((kq << 1)) ^ (ol & 7)) << 3];
                al[m] = *(const short8v*)&rowp[(((kq << 1) | 1) ^ (ol & 7)) << 3];
            }
#pragma unroll
            for (int n = 0; n < 4; ++n) {
                int tr = ncol + n * 16 + r16 + DIL;
                const short* rowp = &Bsl[tr * 64];
                bh[n] = *(const short8v*)&rowp[(((kq << 1)) ^ (tr & 7)) << 3];
                bl[n] = *(const short8v*)&rowp[(((kq << 1) | 1) ^ (tr & 7)) << 3];
            }
#pragma unroll
            for (int m = 0; m < 4; ++m)
#pragma unroll
                for (int n = 0; n < 4; ++n) {
                    acc1[m][n] = __builtin_amdgcn_mfma_f32_16x16x32_bf16(ah[m], bh[n], acc1[m][n], 0, 0, 0);
                    acc1[m][n] = __builtin_amdgcn_mfma_f32_16x16x32_bf16(ah[m], bl[n], acc1[m][n], 0, 0, 0);
                    acc1[m][n] = __builtin_amdgcn_mfma_f32_16x16x32_bf16(al[m], bh[n], acc1[m][n], 0, 0, 0);
                }
        }
    }

    // epilogue
    const unsigned short* phi = tpli;
    const unsigned short* plo = tpli + SLAB;
    unsigned short* ohi = tplo;
    unsigned short* olo = tplo + SLAB;
    float sn[4] = {0.f, 0.f, 0.f, 0.f};
#pragma unroll
    for (int m = 0; m < 4; ++m) {
        int ob4 = obase + mrow + m * 16 + kq * 4;
        float4v bias = *(const float4v*)&bconv[ob4];
#pragma unroll
        for (int n = 0; n < 4; ++n) {
            int t = ncol + n * 16 + r16;
            float rt, rt1;
            if (FIRST) {
                rt = 1.0f; rt1 = 1.0f;
            } else {
                rt = rn[b * kT + t];
                rt1 = (t + DIL < kT) ? rn[b * kT + t + DIL] : 0.0f;
            }
            size_t sidx = ((size_t)b * kT + t) * kC + ob4;
            ushort4v sh = *(const ushort4v*)&phi[sidx];
            ushort4v sl = *(const ushort4v*)&plo[sidx];
            ushort4v hh, hl;
#pragma unroll
            for (int j = 0; j < 4; ++j) {
                float v = rt * acc0[m][n][j] + rt1 * acc1[m][n][j] + bias[j];
                v = v >= 0.f ? v : 0.2f * v;
                float skip = rt * (bf_f(sh[j]) + bf_f(sl[j]));   // = normalized h_{i-1}
                float hp = v + skip;
                sn[n] += hp * hp;
                unsigned short h = bf_hi(hp);
                hh[j] = h;
                hl[j] = bf_hi(hp - bf_f(h));
                if (accmode == 1) {
                    accp[((size_t)b * kC + ob4 + j) * kT + t] = skip;
                } else if (accmode == 2) {
                    accp[((size_t)b * kC + ob4 + j) * kT + t] += skip;
                }
            }
            *(ushort4v*)&ohi[sidx] = hh;
            *(ushort4v*)&olo[sidx] = hl;
        }
    }
#pragma unroll
    for (int n = 0; n < 4; ++n)
        red[w * 256 + kq * 64 + n * 16 + r16] = sn[n];
    __syncthreads();
    if (tid < kT) {
        int t = tid;
        int base = (t < 64) ? 0 : 2;
        int tl = t & 63;
        float s = 0.f;
#pragma unroll
        for (int ww = 0; ww < 2; ++ww)
#pragma unroll
            for (int q = 0; q < 4; ++q)
                s += red[(base + ww) * 256 + q * 64 + tl];
        ssp[((size_t)blockIdx.x * kB + b) * kT + t] = s;
    }
}

// ---------------------------------------------------------------------------
// rnorm[b][t] = 1 / (sqrt(sum over 8 o-block partials) + 1e-8)
// ---------------------------------------------------------------------------
__global__ void normfac(const float* __restrict__ ssp, float* __restrict__ rnv) {
    int b = blockIdx.x;
    int t = threadIdx.x;
    float s = 0.f;
#pragma unroll
    for (int j = 0; j < kOB; ++j) s += ssp[((size_t)j * kB + b) * kT + t];
    rnv[b * kT + t] = 1.0f / (sqrtf(s) + 1e-8f);
}

// ---------------------------------------------------------------------------
// acc += rn8 * H8 (planes [t][c] -> acc [c][t] via LDS transpose)
// ---------------------------------------------------------------------------
__global__ void accfin(const unsigned short* __restrict__ tpl,
                       const float* __restrict__ rnv,
                       float* __restrict__ accp) {
    __shared__ float tile[64][65];
    int b = blockIdx.x;
    int c0 = blockIdx.y * 64;
    int t0 = blockIdx.z * 64;
    int tid = threadIdx.x;
    const unsigned short* thi = tpl;
    const unsigned short* tlo = tpl + SLAB;
    {
        int tr = tid >> 2;               // 64 t-rows
        int cc = (tid & 3) * 16;         // 16 c per thread
        float rt = rnv[b * kT + t0 + tr];
        size_t src = ((size_t)b * kT + t0 + tr) * kC + c0 + cc;
        short8v h0 = *(const short8v*)&thi[src];
        short8v h1 = *(const short8v*)&thi[src + 8];
        short8v l0 = *(const short8v*)&tlo[src];
        short8v l1 = *(const short8v*)&tlo[src + 8];
#pragma unroll
        for (int j = 0; j < 8; ++j) {
            tile[cc + j][tr] = rt * (bf_f((unsigned short)h0[j]) + bf_f((unsigned short)l0[j]));
            tile[cc + 8 + j][tr] = rt * (bf_f((unsigned short)h1[j]) + bf_f((unsigned short)l1[j]));
        }
    }
    __syncthreads();
#pragma unroll
    for (int r = 0; r < 4; ++r) {
        int row = r * 16 + (tid >> 4);
        int col = (tid & 15) * 4;
        size_t idx = ((size_t)b * kC + c0 + row) * kT + t0 + col;
        float4 a = *(const float4*)&accp[idx];
        a.x += tile[row][col + 0];
        a.y += tile[row][col + 1];
        a.z += tile[row][col + 2];
        a.w += tile[row][col + 3];
        *(float4*)&accp[idx] = a;
    }
}

// ---------------------------------------------------------------------------
// switch partials (unchanged, acc layout [b][c][t])
// ---------------------------------------------------------------------------
__global__ void switch_partial(const float* __restrict__ accp,
                               const float* __restrict__ w_sw,
                               float* __restrict__ swp) {
    int b = blockIdx.x;
    int cblk = blockIdx.y;
    int t = threadIdx.x & 127;
    int half = threadIdx.x >> 7;
    int cbase = cblk * 128 + half * 64;
    const float* arow = accp + ((size_t)b * kC + cbase) * kT + t;
    float p = 0.f;
    for (int j = 0; j < 64; ++j) p += w_sw[cbase + j] * arow[(size_t)j * kT];
    __shared__ float red2[2][128];
    red2[half][t] = p;
    __syncthreads();
    if (half == 0)
        swp[((size_t)cblk * kB + b) * kT + t] = red2[0][t] + red2[1][t];
}

// ---------------------------------------------------------------------------
// Top-16 of |switch+b_sw| (unchanged)
// ---------------------------------------------------------------------------
__global__ void topk_kernel(const float* __restrict__ swp,
                            const float* __restrict__ b_sw,
                            float* __restrict__ vals, int* __restrict__ idxs) {
    int b = blockIdx.x;
    int t = threadIdx.x;
    __shared__ float cur[128];
    __shared__ float rv[128];
    __shared__ int ri[128];
    {
        float s = b_sw[0];
#pragma unroll
        for (int j = 0; j < kC / 128; ++j)
            s += swp[((size_t)j * kB + b) * kT + t];
        cur[t] = fabsf(s);
    }
    __syncthreads();
    for (int r = 0; r < kEv; ++r) {
        rv[t] = cur[t];
        ri[t] = t;
        __syncthreads();
        for (int s = 64; s >= 1; s >>= 1) {
            if (t < s) {
                float v2 = rv[t + s];
                int i2 = ri[t + s];
                if (v2 > rv[t] || (v2 == rv[t] && i2 < ri[t])) { rv[t] = v2; ri[t] = i2; }
            }
            __syncthreads();
        }
        if (t == 0) {
            vals[b * kEv + r] = rv[0];
            idxs[b * kEv + r] = ri[0];
            cur[ri[0]] = -1.0f;
        }
        __syncthreads();
    }
}

// ---------------------------------------------------------------------------
// Final (unchanged)
// ---------------------------------------------------------------------------
__global__ void final_kernel(const float* __restrict__ accp,
                             const float* __restrict__ Mt,
                             const float* __restrict__ pbias,
                             const float* __restrict__ b_par,
                             const float* __restrict__ vals,
                             const int* __restrict__ idxs,
                             float* __restrict__ out) {
    int bn = blockIdx.x;
    int b = bn >> 4;
    int tid = threadIdx.x;
    __shared__ float gs[kC];
    __shared__ float redf[4][64];
    int idx = idxs[bn];
    float val = vals[bn];
#pragma unroll
    for (int j = 0; j < 4; ++j) {
        int k = tid * 4 + j;
        gs[k] = accp[((size_t)b * kC + k) * kT + idx];
    }
    __syncthreads();
    int kg = tid >> 6;
    int pp = tid & 63;
    float partial = 0.f;
    if (pp < kPar) {
        for (int j = 0; j < 256; ++j) {
            int k = kg * 256 + j;
            partial += Mt[(size_t)k * kPar + pp] * gs[k];
        }
    }
    redf[kg][pp] = partial;
    __syncthreads();
    if (kg == 0 && pp < kPar) {
        float s = redf[0][pp] + redf[1][pp] + redf[2][pp] + redf[3][pp];
        out[(size_t)bn * kPar + pp] = val * (s + pbias[pp]) + b_par[pp];
    }
}

// ---------------------------------------------------------------------------
extern "C" void kernel_launch(void* const* d_in, const int* in_sizes, int n_in,
                              void* d_out, int out_size, void* d_ws, size_t ws_size,
                              hipStream_t stream) {
    (void)in_sizes; (void)n_in; (void)out_size; (void)ws_size;
    const float* x      = (const float*)d_in[0];
    const float* w_spec = (const float*)d_in[1];
    const float* b_spec = (const float*)d_in[2];
    const float* w_pos  = (const float*)d_in[3];
    const float* b_pos  = (const float*)d_in[4];
    const float* enc_w  = (const float*)d_in[5];
    const float* enc_b  = (const float*)d_in[6];
    const float* w_vec  = (const float*)d_in[7];
    const float* b_vec  = (const float*)d_in[8];
    const float* w_sw   = (const float*)d_in[9];
    const float* b_sw   = (const float*)d_in[10];
    const float* w_par  = (const float*)d_in[11];
    const float* b_par  = (const float*)d_in[12];
    float* out = (float*)d_out;

    unsigned short* tplA = (unsigned short*)d_ws;        // 2*SLAB bf16 (32 MB)
    unsigned short* tplB = tplA + 2 * SLAB;              // 2*SLAB bf16 (32 MB)
    float* acc  = (float*)(tplB + 2 * SLAB);             // SLAB f32 (32 MB)
    unsigned short* wpl = (unsigned short*)(acc + SLAB); // 4*kC*kC (8 MB)
    unsigned short* wsp = wpl + (size_t)4 * kC * kC;     // 2*kC*kC (4 MB)
    float* posproj = (float*)(wsp + (size_t)2 * kC * kC);
    float* ssp   = posproj + (size_t)kC * kT;            // 8*B*T
    float* rnv   = ssp + (size_t)kOB * kB * kT;          // B*T
    float* swp   = rnv + (size_t)kB * kT;                // 8*B*T
    float* vals  = swp + (size_t)kOB * kB * kT;          // B*16
    int*   idxs  = (int*)(vals + kB * kEv);              // B*16
    float* Mt    = (float*)(idxs + kB * kEv);            // 1024*57
    float* pbias = Mt + (size_t)kC * kPar;               // 57

    pos_kernel<<<kC, kT, 0, stream>>>(w_pos, b_pos, posproj);
    mt_kernel<<<kPar + 1, 256, 0, stream>>>(w_par, w_vec, b_vec, Mt, pbias);
    wspec_kernel<<<kC, 256, 0, stream>>>(w_spec, wsp);
    trans0_kernel<<<dim3(kB, kC / 64, kT / 64), NTHR, 0, stream>>>(x, tplB);
    spec_mfma<<<dim3(kC / BM, kB), NTHR, 0, stream>>>(tplB, wsp, b_spec, posproj, tplA);

    const int dils[kLayers] = {1, 2, 4, 8, 16, 32, 64, 1};
    unsigned short* cur = tplA;
    unsigned short* nxt = tplB;
    for (int i = 0; i < kLayers; ++i) {
        const float* wi = enc_w + (size_t)i * kC * kC * 2;
        const float* bi = enc_b + (size_t)i * kC;
        int am = (i == 0) ? 0 : (i == 1 ? 1 : 2);
        wconv_kernel<<<kC, 256, 0, stream>>>(wi, wpl);
        dim3 grid(kC / BM, kB);
        if (i == 0) {
            conv_mfma<1, 1><<<grid, NTHR, 0, stream>>>(cur, wpl, bi, rnv, nxt, ssp, acc, am);
        } else {
            switch (dils[i]) {
                case 1:  conv_mfma<1, 0><<<grid, NTHR, 0, stream>>>(cur, wpl, bi, rnv, nxt, ssp, acc, am); break;
                case 2:  conv_mfma<2, 0><<<grid, NTHR, 0, stream>>>(cur, wpl, bi, rnv, nxt, ssp, acc, am); break;
                case 4:  conv_mfma<4, 0><<<grid, NTHR, 0, stream>>>(cur, wpl, bi, rnv, nxt, ssp, acc, am); break;
                case 8:  conv_mfma<8, 0><<<grid, NTHR, 0, stream>>>(cur, wpl, bi, rnv, nxt, ssp, acc, am); break;
                case 16: conv_mfma<16, 0><<<grid, NTHR, 0, stream>>>(cur, wpl, bi, rnv, nxt, ssp, acc, am); break;
                case 32: conv_mfma<32, 0><<<grid, NTHR, 0, stream>>>(cur, wpl, bi, rnv, nxt, ssp, acc, am); break;
                case 64: conv_mfma<64, 0><<<grid, NTHR, 0, stream>>>(cur, wpl, bi, rnv, nxt, ssp, acc, am); break;
            }
        }
        normfac<<<kB, kT, 0, stream>>>(ssp, rnv);
        unsigned short* tmp = cur; cur = nxt; nxt = tmp;
    }

    // acc += rn8 * H8
    accfin<<<dim3(kB, kC / 64, kT / 64), NTHR, 0, stream>>>(cur, rnv, acc);

    switch_partial<<<dim3(kB, kC / 128), 256, 0, stream>>>(acc, w_sw, swp);
    topk_kernel<<<kB, 128, 0, stream>>>(swp, b_sw, vals, idxs);
    final_kernel<<<kB * kEv, 256, 0, stream>>>(acc, Mt, pbias, b_par, vals, idxs, out);
}